// Round 13
// baseline (312.633 us; speedup 1.0000x reference)
//
#include <hip/hip_runtime.h>
#include <hip/hip_bf16.h>
#include <stdint.h>
#include <math.h>

// Problem constants: B=2, S=2048, D_MODEL=1024, H=16, HD=64

typedef __attribute__((ext_vector_type(8))) __bf16 bf16x8;
typedef __attribute__((ext_vector_type(4))) float f32x4;

__device__ __forceinline__ unsigned short f2bf(float f) {
  unsigned int u = __float_as_uint(f);
  u += 0x7fffu + ((u >> 16) & 1u);   // round-to-nearest-even
  return (unsigned short)(u >> 16);
}

typedef const __attribute__((address_space(1))) unsigned int* gas_ptr;
typedef __attribute__((address_space(3))) unsigned int* las_ptr;
__device__ __forceinline__ void glds16(const void* g, void* l) {
  __builtin_amdgcn_global_load_lds((gas_ptr)g, (las_ptr)l, 16, 0, 0);
}

// ------------------------------------------- convert + RoPE table (z=7)
__global__ __launch_bounds__(256) void cvt_all(
    const float* __restrict__ a0, const float* __restrict__ a1,
    const float* __restrict__ a2, const float* __restrict__ w0,
    const float* __restrict__ w1, const float* __restrict__ w2,
    const float* __restrict__ w3, unsigned short* __restrict__ ws,
    float2* __restrict__ rtab) {
  const int z = blockIdx.z;
  if (z == 7) {   // RoPE table: tab[spos*32+d] = {cos,sin}(spos*10000^(-d/32))
    const int i = blockIdx.x * 256 + threadIdx.x;
    if (i < 65536) {
      const int spos = i >> 5, d = i & 31;
      const double invf = pow(10000.0, -(double)d / 32.0);
      double sn, cs;
      sincos((double)spos * invf, &sn, &cs);
      rtab[i] = make_float2((float)cs, (float)sn);
    }
    return;
  }
  const float* src;
  unsigned short* dst;
  int n;
  if (z == 0)      { src = a0; dst = ws;             n = 4194304; }
  else if (z == 1) { src = a1; dst = ws + 4194304;   n = 4194304; }
  else if (z == 2) { src = a2; dst = ws + 8388608;   n = 4194304; }
  else if (z == 3) { src = w0; dst = ws + 12582912;  n = 1048576; }
  else if (z == 4) { src = w1; dst = ws + 13631488;  n = 1048576; }
  else if (z == 5) { src = w2; dst = ws + 14680064;  n = 1048576; }
  else             { src = w3; dst = ws + 15728640;  n = 1048576; }
  const int n4 = n >> 2;
  for (int i = blockIdx.x * 256 + threadIdx.x; i < n4; i += gridDim.x * 256) {
    float4 f = ((const float4*)src)[i];
    ushort4 u;
    u.x = f2bf(f.x); u.y = f2bf(f.y); u.z = f2bf(f.z); u.w = f2bf(f.w);
    ((ushort4*)dst)[i] = u;
  }
}

// ------------------------------------------------------------- QKV GEMM
// BK=64, XCD-chunked block swizzle: lin -> (lin%8)*32 + lin/8 so each XCD's
// round-robin share is 32 contiguous blocks (4 A-panels + 8 W-panels, L2-fit).
__global__ __launch_bounds__(256) void gemm_qkv(
    const unsigned short* __restrict__ xq, const unsigned short* __restrict__ xk,
    const unsigned short* __restrict__ xv, const unsigned short* __restrict__ wq,
    const unsigned short* __restrict__ wk, const unsigned short* __restrict__ wv,
    const float* __restrict__ bq, const float* __restrict__ bk,
    const float* __restrict__ bv, const float2* __restrict__ rtab,
    unsigned short* __restrict__ qo, unsigned short* __restrict__ ko,
    unsigned short* __restrict__ vo) {
  const int z = blockIdx.z;  // 0=q 1=k 2=v
  const unsigned short* A = (z == 0) ? xq : (z == 1) ? xk : xv;
  const unsigned short* W = (z == 0) ? wq : (z == 1) ? wk : wv;
  const float* bias = (z == 0) ? bq : (z == 1) ? bk : bv;
  unsigned short* out = (z == 0) ? qo : (z == 1) ? ko : vo;

  const int t = threadIdx.x;
  const int lane = t & 63, wave = t >> 6;
  const int wr = wave >> 1, wc = wave & 1;
  const int lrow = lane & 15, lkb = lane >> 4;
  const int lin = blockIdx.x + (blockIdx.y << 3);      // 0..255
  const int nl = ((lin & 7) << 5) | (lin >> 3);        // XCD-chunked remap
  const int m0 = (nl >> 3) * 128, n0 = (nl & 7) * 128;

  __shared__ __align__(16) unsigned short abuf[8192];   // [kb 0..7][row 0..127][8]
  __shared__ __align__(16) unsigned short bbuf[8192];

  f32x4 acc[4][4] = {};

  for (int k0 = 0; k0 < 1024; k0 += 64) {
    __syncthreads();
#pragma unroll
    for (int i = 0; i < 4; ++i) {
      int slot = i * 256 + t;                 // 0..1023
      int kb = slot >> 7, row = slot & 127;   // kb 0..7
      glds16(A + (size_t)(m0 + row) * 1024 + k0 + kb * 8, &abuf[slot * 8]);
      glds16(W + (size_t)(n0 + row) * 1024 + k0 + kb * 8, &bbuf[slot * 8]);
    }
    __syncthreads();
#pragma unroll
    for (int ks = 0; ks < 2; ++ks) {
      bf16x8 af[4], bfr[4];
#pragma unroll
      for (int mi = 0; mi < 4; ++mi)
        af[mi] = *(const bf16x8*)&abuf[((ks * 4 + lkb) * 128 + wr * 64 + mi * 16 + lrow) * 8];
#pragma unroll
      for (int ni = 0; ni < 4; ++ni)
        bfr[ni] = *(const bf16x8*)&bbuf[((ks * 4 + lkb) * 128 + wc * 64 + ni * 16 + lrow) * 8];
#pragma unroll
      for (int mi = 0; mi < 4; ++mi)
#pragma unroll
        for (int ni = 0; ni < 4; ++ni)
          acc[mi][ni] = __builtin_amdgcn_mfma_f32_16x16x32_bf16(af[mi], bfr[ni],
                                                                acc[mi][ni], 0, 0, 0);
    }
  }

  const int nbase = n0 + wc * 64;
  float bias_v[4];
#pragma unroll
  for (int ni = 0; ni < 4; ++ni) bias_v[ni] = bias[nbase + ni * 16 + lrow];

  const int mbase = m0 + wr * 64 + 4 * lkb;
  const bool rope = (z < 2);
  const float qsc = (z == 0) ? 0.125f : 1.0f;

#pragma unroll
  for (int mi = 0; mi < 4; ++mi) {
#pragma unroll
    for (int r = 0; r < 4; ++r) {
      const int m = mbase + mi * 16 + r;
      const int bidx = m >> 11, spos = m & 2047;
      float vals[4];
#pragma unroll
      for (int ni = 0; ni < 4; ++ni) vals[ni] = acc[mi][ni][r] + bias_v[ni];
      if (rope) {
#pragma unroll
        for (int ni = 0; ni < 2; ++ni) {
          const int d = ni * 16 + lrow;  // 0..31
          const float2 cs2 = rtab[spos * 32 + d];
          float x1 = vals[ni], x2 = vals[ni + 2];
          vals[ni] = (x1 * cs2.x - x2 * cs2.y) * qsc;
          vals[ni + 2] = (x2 * cs2.x + x1 * cs2.y) * qsc;
        }
      }
#pragma unroll
      for (int ni = 0; ni < 4; ++ni) {
        const int n = nbase + ni * 16 + lrow;
        const int h = n >> 6, d = n & 63;
        out[(size_t)((bidx * 16 + h) * 2048 + spos) * 64 + d] = f2bf(vals[ni]);
      }
    }
  }
}

// ------------------------------------------------------------- out GEMM (BK=64, swizzled)
__global__ __launch_bounds__(256) void gemm_out(
    const unsigned short* __restrict__ A, const unsigned short* __restrict__ W,
    const float* __restrict__ bias, float* __restrict__ out) {
  const int t = threadIdx.x;
  const int lane = t & 63, wave = t >> 6;
  const int wr = wave >> 1, wc = wave & 1;
  const int lrow = lane & 15, lkb = lane >> 4;
  const int lin = blockIdx.x + (blockIdx.y << 3);
  const int nl = ((lin & 7) << 5) | (lin >> 3);
  const int m0 = (nl >> 3) * 128, n0 = (nl & 7) * 128;

  __shared__ __align__(16) unsigned short abuf[8192];
  __shared__ __align__(16) unsigned short bbuf[8192];

  f32x4 acc[4][4] = {};

  for (int k0 = 0; k0 < 1024; k0 += 64) {
    __syncthreads();
#pragma unroll
    for (int i = 0; i < 4; ++i) {
      int slot = i * 256 + t;
      int kb = slot >> 7, row = slot & 127;
      glds16(A + (size_t)(m0 + row) * 1024 + k0 + kb * 8, &abuf[slot * 8]);
      glds16(W + (size_t)(n0 + row) * 1024 + k0 + kb * 8, &bbuf[slot * 8]);
    }
    __syncthreads();
#pragma unroll
    for (int ks = 0; ks < 2; ++ks) {
      bf16x8 af[4], bfr[4];
#pragma unroll
      for (int mi = 0; mi < 4; ++mi)
        af[mi] = *(const bf16x8*)&abuf[((ks * 4 + lkb) * 128 + wr * 64 + mi * 16 + lrow) * 8];
#pragma unroll
      for (int ni = 0; ni < 4; ++ni)
        bfr[ni] = *(const bf16x8*)&bbuf[((ks * 4 + lkb) * 128 + wc * 64 + ni * 16 + lrow) * 8];
#pragma unroll
      for (int mi = 0; mi < 4; ++mi)
#pragma unroll
        for (int ni = 0; ni < 4; ++ni)
          acc[mi][ni] = __builtin_amdgcn_mfma_f32_16x16x32_bf16(af[mi], bfr[ni],
                                                                acc[mi][ni], 0, 0, 0);
    }
  }

  const int nbase = n0 + wc * 64;
  float bias_v[4];
#pragma unroll
  for (int ni = 0; ni < 4; ++ni) bias_v[ni] = bias[nbase + ni * 16 + lrow];
  const int mbase = m0 + wr * 64 + 4 * lkb;
#pragma unroll
  for (int mi = 0; mi < 4; ++mi)
#pragma unroll
    for (int r = 0; r < 4; ++r) {
      const int m = mbase + mi * 16 + r;
      float* orow = out + (size_t)m * 1024 + nbase;
#pragma unroll
      for (int ni = 0; ni < 4; ++ni)
        orow[ni * 16 + lrow] = acc[mi][ni][r] + bias_v[ni];
    }
}

// --------------------------------------------------------- V transpose
// v [BH, S, 64] -> vT [BH, 64, S]
__global__ __launch_bounds__(256) void transpose_v(
    const unsigned short* __restrict__ v, unsigned short* __restrict__ vt) {
  const int s0 = blockIdx.x * 64;
  const int bh = blockIdx.y;
  __shared__ __align__(16) unsigned short tile[64][80];
  const int t = threadIdx.x;
  {
    const int row = t >> 2, cb = t & 3;
    const unsigned short* src = v + (size_t)(bh * 2048 + s0 + row) * 64 + cb * 16;
    *(uint4*)&tile[row][cb * 16] = *(const uint4*)src;
    *(uint4*)&tile[row][cb * 16 + 8] = *(const uint4*)(src + 8);
  }
  __syncthreads();
  {
    const int d = t >> 2, sc = t & 3;
    __align__(16) unsigned short tmp[16];
#pragma unroll
    for (int u = 0; u < 16; ++u) tmp[u] = tile[sc * 16 + u][d];
    unsigned short* dst = vt + (size_t)(bh * 64 + d) * 2048 + s0 + sc * 16;
    *(uint4*)dst = *(const uint4*)&tmp[0];
    *(uint4*)(dst + 8) = *(const uint4*)&tmp[8];
  }
}

// ----------------------------------------------------------- attention
// R9-structure + NON-TEMPORAL attn stores (attn stream has zero reuse; keep
// K/vT L2-resident for the 16x per-bh staging re-reads).
__global__ __launch_bounds__(256) void attn_kernel(
    const unsigned short* __restrict__ Q, const unsigned short* __restrict__ Km,
    const unsigned short* __restrict__ Vt, float* __restrict__ attn,
    unsigned short* __restrict__ ctx) {
  const int p = blockIdx.x;          // 0..15
  const int qta = p, qtb = 31 - p;
  const int bh = blockIdx.y;
  const int t = threadIdx.x;
  const int lane = t & 63, wave = t >> 6;
  const int lrow = lane & 15, lg = lane >> 4;
  const int wq0a = qta * 64 + wave * 16;
  const int wq0b = qtb * 64 + wave * 16;

  const unsigned short* Qb = Q + (size_t)bh * 2048 * 64;
  const unsigned short* Kb = Km + (size_t)bh * 2048 * 64;
  const unsigned short* Vb = Vt + (size_t)bh * 64 * 2048;
  float* attn_b = attn + (size_t)bh * 2048 * 2048;

  __shared__ __align__(16) unsigned short kbuf[4096];
  __shared__ __align__(16) unsigned short vbuf[4096];
  __shared__ __align__(16) unsigned short pbuf[4][1024];

  bf16x8 qfa[2], qfb[2];
#pragma unroll
  for (int dk = 0; dk < 2; ++dk) {
    qfa[dk] = *(const bf16x8*)(Qb + (size_t)(wq0a + lrow) * 64 + dk * 32 + lg * 8);
    qfb[dk] = *(const bf16x8*)(Qb + (size_t)(wq0b + lrow) * 64 + dk * 32 + lg * 8);
  }

  float l_a[4] = {0.f, 0.f, 0.f, 0.f};
  float l_b[4] = {0.f, 0.f, 0.f, 0.f};

  auto lupdate = [&](const unsigned short* buf, int kbase, int wq0,
                     const bf16x8* qf, float* l_loc) {
    f32x4 s[4] = {};
#pragma unroll
    for (int fc = 0; fc < 4; ++fc)
#pragma unroll
      for (int dk = 0; dk < 2; ++dk) {
        bf16x8 kf = *(const bf16x8*)&buf[((dk * 4 + lg) * 64 + fc * 16 + lrow) * 8];
        s[fc] = __builtin_amdgcn_mfma_f32_16x16x32_bf16(qf[dk], kf, s[fc], 0, 0, 0);
      }
#pragma unroll
    for (int r = 0; r < 4; ++r) {
      const int qg = wq0 + 4 * lg + r;
      float sum = 0.f;
#pragma unroll
      for (int fc = 0; fc < 4; ++fc) {
        const int kg = kbase + fc * 16 + lrow;
        sum += __expf((kg <= qg) ? s[fc][r] : -1e30f);
      }
      l_loc[r] += sum;
    }
  };

  // -------- pass 1: denominators for both q-tiles (2 K-tiles/barrier pair)
  for (int kt = 0; kt <= qtb; kt += 2) {
    const int k0 = kt * 64;
    const bool two = (kt + 1) <= qtb;
    __syncthreads();
#pragma unroll
    for (int i = 0; i < 2; ++i) {
      int slot = i * 256 + t;
      int cb = slot >> 6, row = slot & 63;
      glds16(Kb + (size_t)(k0 + row) * 64 + cb * 8, &kbuf[slot * 8]);
      if (two)
        glds16(Kb + (size_t)(k0 + 64 + row) * 64 + cb * 8, &vbuf[slot * 8]);
    }
    __syncthreads();
    if (kt <= qta) lupdate(kbuf, k0, wq0a, qfa, l_a);
    lupdate(kbuf, k0, wq0b, qfb, l_b);
    if (two) {
      if (kt + 1 <= qta) lupdate(vbuf, k0 + 64, wq0a, qfa, l_a);
      lupdate(vbuf, k0 + 64, wq0b, qfb, l_b);
    }
  }

  float loglinva[4], loglinvb[4];
#pragma unroll
  for (int r = 0; r < 4; ++r) {
    float la = l_a[r], lb = l_b[r];
#pragma unroll
    for (int off = 1; off < 16; off <<= 1) {
      la += __shfl_xor(la, off);
      lb += __shfl_xor(lb, off);
    }
    loglinva[r] = -__logf(la);
    loglinvb[r] = -__logf(lb);
  }

  // -------- pass 2: scores -> attn store (NT) + PV, both q-tiles per staging
  f32x4 oaa[4] = {};
  f32x4 oab[4] = {};

  auto process = [&](int k0, int wq0, const bf16x8* qf, const float* loglinv,
                     f32x4* oa) {
    f32x4 s[4] = {};
#pragma unroll
    for (int fc = 0; fc < 4; ++fc)
#pragma unroll
      for (int dk = 0; dk < 2; ++dk) {
        bf16x8 kf = *(const bf16x8*)&kbuf[((dk * 4 + lg) * 64 + fc * 16 + lrow) * 8];
        s[fc] = __builtin_amdgcn_mfma_f32_16x16x32_bf16(qf[dk], kf, s[fc], 0, 0, 0);
      }
#pragma unroll
    for (int r = 0; r < 4; ++r) {
      const int qg = wq0 + 4 * lg + r;
      const int q_ = 4 * lg + r;
      float* arow = attn_b + (size_t)qg * 2048 + k0;
#pragma unroll
      for (int fc = 0; fc < 4; ++fc) {
        const int kg = k0 + fc * 16 + lrow;
        const float pv = (kg <= qg) ? __expf(s[fc][r] + loglinv[r]) : 0.f;
        __builtin_nontemporal_store(pv, arow + fc * 16 + lrow);
        // scatter into per-wave P buffer in MFMA-A layout (XOR swizzled)
        const int k_ = fc * 16 + lrow;
        const int dl = q_ + 16 * ((k_ >> 3) & 3);
        const int kk = k_ >> 5, j = k_ & 7;
        int byteo = (kk * 64 + dl) * 16 + j * 2;
        byteo ^= ((kk * 8 + (dl >> 3)) & 7) << 4;
        *(unsigned short*)((char*)pbuf[wave] + byteo) = f2bf(pv);
      }
    }
#pragma unroll
    for (int kk = 0; kk < 2; ++kk) {
      int rbyte = (kk * 64 + lane) * 16;
      rbyte ^= ((kk * 8 + (lane >> 3)) & 7) << 4;
      bf16x8 pa = *(const bf16x8*)((char*)pbuf[wave] + rbyte);
#pragma unroll
      for (int fd = 0; fd < 4; ++fd) {
        bf16x8 vf = *(const bf16x8*)&vbuf[((kk * 4 + lg) * 64 + fd * 16 + lrow) * 8];
        oa[fd] = __builtin_amdgcn_mfma_f32_16x16x32_bf16(pa, vf, oa[fd], 0, 0, 0);
      }
    }
  };

  for (int kt = 0; kt <= qtb; ++kt) {
    const int k0 = kt * 64;
    __syncthreads();
#pragma unroll
    for (int i = 0; i < 2; ++i) {
      int slot = i * 256 + t;
      int cb = slot >> 6, row = slot & 63;
      glds16(Kb + (size_t)(k0 + row) * 64 + cb * 8, &kbuf[slot * 8]);
      glds16(Vb + (size_t)row * 2048 + k0 + cb * 8, &vbuf[slot * 8]);
    }
    __syncthreads();
    if (kt <= qta) process(k0, wq0a, qfa, loglinva, oaa);
    process(k0, wq0b, qfb, loglinvb, oab);
  }

  // -------- zero-fill non-causal region (vectorized, NT), both q-tiles
  {
    const f32x4 z4 = {0.f, 0.f, 0.f, 0.f};
    const int zc0a = (qta + 1) * 16;
    for (int rr = 0; rr < 16; ++rr) {
      f32x4* arow = (f32x4*)(attn_b + (size_t)(wq0a + rr) * 2048);
      for (int c = zc0a + lane; c < 512; c += 64)
        __builtin_nontemporal_store(z4, arow + c);
    }
    const int zc0b = (qtb + 1) * 16;
    for (int rr = 0; rr < 16; ++rr) {
      f32x4* arow = (f32x4*)(attn_b + (size_t)(wq0b + rr) * 2048);
      for (int c = zc0b + lane; c < 512; c += 64)
        __builtin_nontemporal_store(z4, arow + c);
    }
  }

  // -------- ctx store [B,S,1024] bf16, both q-tiles
  const int bidx = bh >> 4, h = bh & 15;
#pragma unroll
  for (int fd = 0; fd < 4; ++fd)
#pragma unroll
    for (int r = 0; r < 4; ++r) {
      const int qga = wq0a + 4 * lg + r;
      const int qgb = wq0b + 4 * lg + r;
      ctx[(size_t)(bidx * 2048 + qga) * 1024 + h * 64 + fd * 16 + lrow] =
          f2bf(oaa[fd][r]);
      ctx[(size_t)(bidx * 2048 + qgb) * 1024 + h * 64 + fd * 16 + lrow] =
          f2bf(oab[fd][r]);
    }
}

// ---------------------------------------------------------------- launch
extern "C" void kernel_launch(void* const* d_in, const int* in_sizes, int n_in,
                              void* d_out, int out_size, void* d_ws, size_t ws_size,
                              hipStream_t stream) {
  const float* q_in = (const float*)d_in[0];
  const float* k_in = (const float*)d_in[1];
  const float* v_in = (const float*)d_in[2];
  const float* Wq = (const float*)d_in[3];
  const float* bq = (const float*)d_in[4];
  const float* Wk = (const float*)d_in[5];
  const float* bk = (const float*)d_in[6];
  const float* Wv = (const float*)d_in[7];
  const float* bv = (const float*)d_in[8];
  const float* Wo = (const float*)d_in[9];
  const float* bo = (const float*)d_in[10];

  unsigned short* ws = (unsigned short*)d_ws;
  float* outp = (float*)d_out;

  // ws offsets in ushort units
  const size_t OXQ = 0, OXK = 4194304, OXV = 8388608;
  const size_t OWQ = 12582912, OWK = 13631488, OWV = 14680064, OWO = 15728640;
  const size_t OQ = 16777216, OK = 20971520, OV = 25165824;
  const size_t OTAB = 29360128;  // 2048*32 float2 = 262144 ushorts
  const size_t OVT = OXK;   // xk dead after QKV GEMM
  const size_t OCTX = OXQ;  // xq dead after QKV GEMM
  float2* rtab = (float2*)(ws + OTAB);

  cvt_all<<<dim3(512, 1, 8), 256, 0, stream>>>(q_in, k_in, v_in, Wq, Wk, Wv, Wo,
                                               ws, rtab);
  gemm_qkv<<<dim3(8, 32, 3), 256, 0, stream>>>(ws + OXQ, ws + OXK, ws + OXV,
                                               ws + OWQ, ws + OWK, ws + OWV,
                                               bq, bk, bv, rtab,
                                               ws + OQ, ws + OK, ws + OV);
  transpose_v<<<dim3(32, 32), 256, 0, stream>>>(ws + OV, ws + OVT);
  attn_kernel<<<dim3(16, 32), 256, 0, stream>>>(ws + OQ, ws + OK, ws + OVT,
                                                outp + 4194304, ws + OCTX);
  gemm_out<<<dim3(8, 32), 256, 0, stream>>>(ws + OCTX, ws + OWO, bo, outp);
}

// Round 14
// 292.905 us; speedup vs baseline: 1.0674x; 1.0674x over previous
//
#include <hip/hip_runtime.h>
#include <hip/hip_bf16.h>
#include <stdint.h>
#include <math.h>

// Problem constants: B=2, S=2048, D_MODEL=1024, H=16, HD=64

typedef __attribute__((ext_vector_type(8))) __bf16 bf16x8;
typedef __attribute__((ext_vector_type(4))) float f32x4;

__device__ __forceinline__ unsigned short f2bf(float f) {
  unsigned int u = __float_as_uint(f);
  u += 0x7fffu + ((u >> 16) & 1u);   // round-to-nearest-even
  return (unsigned short)(u >> 16);
}

typedef const __attribute__((address_space(1))) unsigned int* gas_ptr;
typedef __attribute__((address_space(3))) unsigned int* las_ptr;
__device__ __forceinline__ void glds16(const void* g, void* l) {
  __builtin_amdgcn_global_load_lds((gas_ptr)g, (las_ptr)l, 16, 0, 0);
}

// ------------------------------------------- convert + RoPE table (z=7)
__global__ __launch_bounds__(256) void cvt_all(
    const float* __restrict__ a0, const float* __restrict__ a1,
    const float* __restrict__ a2, const float* __restrict__ w0,
    const float* __restrict__ w1, const float* __restrict__ w2,
    const float* __restrict__ w3, unsigned short* __restrict__ ws,
    float2* __restrict__ rtab) {
  const int z = blockIdx.z;
  if (z == 7) {   // RoPE table: tab[spos*32+d] = {cos,sin}(spos*10000^(-d/32))
    const int i = blockIdx.x * 256 + threadIdx.x;
    if (i < 65536) {
      const int spos = i >> 5, d = i & 31;
      const double invf = pow(10000.0, -(double)d / 32.0);
      double sn, cs;
      sincos((double)spos * invf, &sn, &cs);
      rtab[i] = make_float2((float)cs, (float)sn);
    }
    return;
  }
  const float* src;
  unsigned short* dst;
  int n;
  if (z == 0)      { src = a0; dst = ws;             n = 4194304; }
  else if (z == 1) { src = a1; dst = ws + 4194304;   n = 4194304; }
  else if (z == 2) { src = a2; dst = ws + 8388608;   n = 4194304; }
  else if (z == 3) { src = w0; dst = ws + 12582912;  n = 1048576; }
  else if (z == 4) { src = w1; dst = ws + 13631488;  n = 1048576; }
  else if (z == 5) { src = w2; dst = ws + 14680064;  n = 1048576; }
  else             { src = w3; dst = ws + 15728640;  n = 1048576; }
  const int n4 = n >> 2;
  for (int i = blockIdx.x * 256 + threadIdx.x; i < n4; i += gridDim.x * 256) {
    float4 f = ((const float4*)src)[i];
    ushort4 u;
    u.x = f2bf(f.x); u.y = f2bf(f.y); u.z = f2bf(f.z); u.w = f2bf(f.w);
    ((ushort4*)dst)[i] = u;
  }
}

// ------------------------------------------------------------- QKV GEMM
// BK=64, XCD-chunked block swizzle: lin -> (lin%8)*32 + lin/8 so each XCD's
// round-robin share is 32 contiguous blocks (4 A-panels + 8 W-panels, L2-fit).
__global__ __launch_bounds__(256) void gemm_qkv(
    const unsigned short* __restrict__ xq, const unsigned short* __restrict__ xk,
    const unsigned short* __restrict__ xv, const unsigned short* __restrict__ wq,
    const unsigned short* __restrict__ wk, const unsigned short* __restrict__ wv,
    const float* __restrict__ bq, const float* __restrict__ bk,
    const float* __restrict__ bv, const float2* __restrict__ rtab,
    unsigned short* __restrict__ qo, unsigned short* __restrict__ ko,
    unsigned short* __restrict__ vo) {
  const int z = blockIdx.z;  // 0=q 1=k 2=v
  const unsigned short* A = (z == 0) ? xq : (z == 1) ? xk : xv;
  const unsigned short* W = (z == 0) ? wq : (z == 1) ? wk : wv;
  const float* bias = (z == 0) ? bq : (z == 1) ? bk : bv;
  unsigned short* out = (z == 0) ? qo : (z == 1) ? ko : vo;

  const int t = threadIdx.x;
  const int lane = t & 63, wave = t >> 6;
  const int wr = wave >> 1, wc = wave & 1;
  const int lrow = lane & 15, lkb = lane >> 4;
  const int lin = blockIdx.x + (blockIdx.y << 3);      // 0..255
  const int nl = ((lin & 7) << 5) | (lin >> 3);        // XCD-chunked remap
  const int m0 = (nl >> 3) * 128, n0 = (nl & 7) * 128;

  __shared__ __align__(16) unsigned short abuf[8192];   // [kb 0..7][row 0..127][8]
  __shared__ __align__(16) unsigned short bbuf[8192];

  f32x4 acc[4][4] = {};

  for (int k0 = 0; k0 < 1024; k0 += 64) {
    __syncthreads();
#pragma unroll
    for (int i = 0; i < 4; ++i) {
      int slot = i * 256 + t;                 // 0..1023
      int kb = slot >> 7, row = slot & 127;   // kb 0..7
      glds16(A + (size_t)(m0 + row) * 1024 + k0 + kb * 8, &abuf[slot * 8]);
      glds16(W + (size_t)(n0 + row) * 1024 + k0 + kb * 8, &bbuf[slot * 8]);
    }
    __syncthreads();
#pragma unroll
    for (int ks = 0; ks < 2; ++ks) {
      bf16x8 af[4], bfr[4];
#pragma unroll
      for (int mi = 0; mi < 4; ++mi)
        af[mi] = *(const bf16x8*)&abuf[((ks * 4 + lkb) * 128 + wr * 64 + mi * 16 + lrow) * 8];
#pragma unroll
      for (int ni = 0; ni < 4; ++ni)
        bfr[ni] = *(const bf16x8*)&bbuf[((ks * 4 + lkb) * 128 + wc * 64 + ni * 16 + lrow) * 8];
#pragma unroll
      for (int mi = 0; mi < 4; ++mi)
#pragma unroll
        for (int ni = 0; ni < 4; ++ni)
          acc[mi][ni] = __builtin_amdgcn_mfma_f32_16x16x32_bf16(af[mi], bfr[ni],
                                                                acc[mi][ni], 0, 0, 0);
    }
  }

  const int nbase = n0 + wc * 64;
  float bias_v[4];
#pragma unroll
  for (int ni = 0; ni < 4; ++ni) bias_v[ni] = bias[nbase + ni * 16 + lrow];

  const int mbase = m0 + wr * 64 + 4 * lkb;
  const bool rope = (z < 2);
  const float qsc = (z == 0) ? 0.125f : 1.0f;

#pragma unroll
  for (int mi = 0; mi < 4; ++mi) {
#pragma unroll
    for (int r = 0; r < 4; ++r) {
      const int m = mbase + mi * 16 + r;
      const int bidx = m >> 11, spos = m & 2047;
      float vals[4];
#pragma unroll
      for (int ni = 0; ni < 4; ++ni) vals[ni] = acc[mi][ni][r] + bias_v[ni];
      if (rope) {
#pragma unroll
        for (int ni = 0; ni < 2; ++ni) {
          const int d = ni * 16 + lrow;  // 0..31
          const float2 cs2 = rtab[spos * 32 + d];
          float x1 = vals[ni], x2 = vals[ni + 2];
          vals[ni] = (x1 * cs2.x - x2 * cs2.y) * qsc;
          vals[ni + 2] = (x2 * cs2.x + x1 * cs2.y) * qsc;
        }
      }
#pragma unroll
      for (int ni = 0; ni < 4; ++ni) {
        const int n = nbase + ni * 16 + lrow;
        const int h = n >> 6, d = n & 63;
        out[(size_t)((bidx * 16 + h) * 2048 + spos) * 64 + d] = f2bf(vals[ni]);
      }
    }
  }
}

// ------------------------------------------------------------- out GEMM (BK=64, swizzled)
__global__ __launch_bounds__(256) void gemm_out(
    const unsigned short* __restrict__ A, const unsigned short* __restrict__ W,
    const float* __restrict__ bias, float* __restrict__ out) {
  const int t = threadIdx.x;
  const int lane = t & 63, wave = t >> 6;
  const int wr = wave >> 1, wc = wave & 1;
  const int lrow = lane & 15, lkb = lane >> 4;
  const int lin = blockIdx.x + (blockIdx.y << 3);
  const int nl = ((lin & 7) << 5) | (lin >> 3);
  const int m0 = (nl >> 3) * 128, n0 = (nl & 7) * 128;

  __shared__ __align__(16) unsigned short abuf[8192];
  __shared__ __align__(16) unsigned short bbuf[8192];

  f32x4 acc[4][4] = {};

  for (int k0 = 0; k0 < 1024; k0 += 64) {
    __syncthreads();
#pragma unroll
    for (int i = 0; i < 4; ++i) {
      int slot = i * 256 + t;
      int kb = slot >> 7, row = slot & 127;
      glds16(A + (size_t)(m0 + row) * 1024 + k0 + kb * 8, &abuf[slot * 8]);
      glds16(W + (size_t)(n0 + row) * 1024 + k0 + kb * 8, &bbuf[slot * 8]);
    }
    __syncthreads();
#pragma unroll
    for (int ks = 0; ks < 2; ++ks) {
      bf16x8 af[4], bfr[4];
#pragma unroll
      for (int mi = 0; mi < 4; ++mi)
        af[mi] = *(const bf16x8*)&abuf[((ks * 4 + lkb) * 128 + wr * 64 + mi * 16 + lrow) * 8];
#pragma unroll
      for (int ni = 0; ni < 4; ++ni)
        bfr[ni] = *(const bf16x8*)&bbuf[((ks * 4 + lkb) * 128 + wc * 64 + ni * 16 + lrow) * 8];
#pragma unroll
      for (int mi = 0; mi < 4; ++mi)
#pragma unroll
        for (int ni = 0; ni < 4; ++ni)
          acc[mi][ni] = __builtin_amdgcn_mfma_f32_16x16x32_bf16(af[mi], bfr[ni],
                                                                acc[mi][ni], 0, 0, 0);
    }
  }

  const int nbase = n0 + wc * 64;
  float bias_v[4];
#pragma unroll
  for (int ni = 0; ni < 4; ++ni) bias_v[ni] = bias[nbase + ni * 16 + lrow];
  const int mbase = m0 + wr * 64 + 4 * lkb;
#pragma unroll
  for (int mi = 0; mi < 4; ++mi)
#pragma unroll
    for (int r = 0; r < 4; ++r) {
      const int m = mbase + mi * 16 + r;
      float* orow = out + (size_t)m * 1024 + nbase;
#pragma unroll
      for (int ni = 0; ni < 4; ++ni)
        orow[ni * 16 + lrow] = acc[mi][ni][r] + bias_v[ni];
    }
}

// --------------------------------------------------------- V transpose
// v [BH, S, 64] -> vT [BH, 64, S]
__global__ __launch_bounds__(256) void transpose_v(
    const unsigned short* __restrict__ v, unsigned short* __restrict__ vt) {
  const int s0 = blockIdx.x * 64;
  const int bh = blockIdx.y;
  __shared__ __align__(16) unsigned short tile[64][80];
  const int t = threadIdx.x;
  {
    const int row = t >> 2, cb = t & 3;
    const unsigned short* src = v + (size_t)(bh * 2048 + s0 + row) * 64 + cb * 16;
    *(uint4*)&tile[row][cb * 16] = *(const uint4*)src;
    *(uint4*)&tile[row][cb * 16 + 8] = *(const uint4*)(src + 8);
  }
  __syncthreads();
  {
    const int d = t >> 2, sc = t & 3;
    __align__(16) unsigned short tmp[16];
#pragma unroll
    for (int u = 0; u < 16; ++u) tmp[u] = tile[sc * 16 + u][d];
    unsigned short* dst = vt + (size_t)(bh * 64 + d) * 2048 + s0 + sc * 16;
    *(uint4*)dst = *(const uint4*)&tmp[0];
    *(uint4*)(dst + 8) = *(const uint4*)&tmp[8];
  }
}

// ----------------------------------------------------------- attention
// 8-wave blocks: waves 0-3 own q-tile p, waves 4-7 own q-tile 31-p, processed
// CONCURRENTLY per staging (was sequential in 4 waves). 2x waves/CU for
// latency hiding; staging/barrier count unchanged; plain stores (NT regressed).
__global__ __launch_bounds__(512) void attn_kernel(
    const unsigned short* __restrict__ Q, const unsigned short* __restrict__ Km,
    const unsigned short* __restrict__ Vt, float* __restrict__ attn,
    unsigned short* __restrict__ ctx) {
  const int p = blockIdx.x;          // 0..15
  const int qta = p, qtb = 31 - p;
  const int bh = blockIdx.y;
  const int t = threadIdx.x;
  const int lane = t & 63, wave = t >> 6;          // wave 0..7
  const int wtile = wave >> 2, wid = wave & 3;     // wtile 0=a, 1=b
  const int lrow = lane & 15, lg = lane >> 4;
  const int myqt = wtile ? qtb : qta;
  const int wq0 = myqt * 64 + wid * 16;

  const unsigned short* Qb = Q + (size_t)bh * 2048 * 64;
  const unsigned short* Kb = Km + (size_t)bh * 2048 * 64;
  const unsigned short* Vb = Vt + (size_t)bh * 64 * 2048;
  float* attn_b = attn + (size_t)bh * 2048 * 2048;

  __shared__ __align__(16) unsigned short kbuf[4096];
  __shared__ __align__(16) unsigned short vbuf[4096];
  __shared__ __align__(16) unsigned short pbuf[8][1024];

  bf16x8 qf[2];
#pragma unroll
  for (int dk = 0; dk < 2; ++dk)
    qf[dk] = *(const bf16x8*)(Qb + (size_t)(wq0 + lrow) * 64 + dk * 32 + lg * 8);

  float l_loc[4] = {0.f, 0.f, 0.f, 0.f};

  auto lupdate = [&](const unsigned short* buf, int kbase) {
    f32x4 s[4] = {};
#pragma unroll
    for (int fc = 0; fc < 4; ++fc)
#pragma unroll
      for (int dk = 0; dk < 2; ++dk) {
        bf16x8 kf = *(const bf16x8*)&buf[((dk * 4 + lg) * 64 + fc * 16 + lrow) * 8];
        s[fc] = __builtin_amdgcn_mfma_f32_16x16x32_bf16(qf[dk], kf, s[fc], 0, 0, 0);
      }
#pragma unroll
    for (int r = 0; r < 4; ++r) {
      const int qg = wq0 + 4 * lg + r;
      float sum = 0.f;
#pragma unroll
      for (int fc = 0; fc < 4; ++fc) {
        const int kg = kbase + fc * 16 + lrow;
        sum += __expf((kg <= qg) ? s[fc][r] : -1e30f);
      }
      l_loc[r] += sum;
    }
  };

  // -------- pass 1: denominators (2 K-tiles per barrier pair; 512-thread staging)
  for (int kt = 0; kt <= qtb; kt += 2) {
    const int k0 = kt * 64;
    const bool two = (kt + 1) <= qtb;
    __syncthreads();
    {
      int cb = t >> 6, row = t & 63;   // t = 0..511
      glds16(Kb + (size_t)(k0 + row) * 64 + cb * 8, &kbuf[t * 8]);
      if (two)
        glds16(Kb + (size_t)(k0 + 64 + row) * 64 + cb * 8, &vbuf[t * 8]);
    }
    __syncthreads();
    if (kt <= myqt) lupdate(kbuf, k0);
    if (two && (kt + 1) <= myqt) lupdate(vbuf, k0 + 64);
  }

  float loglinv[4];
#pragma unroll
  for (int r = 0; r < 4; ++r) {
    float l = l_loc[r];
#pragma unroll
    for (int off = 1; off < 16; off <<= 1) l += __shfl_xor(l, off);
    loglinv[r] = -__logf(l);
  }

  // -------- pass 2: scores -> attn store + PV (each wave its own tile)
  f32x4 oa[4] = {};

  for (int kt = 0; kt <= qtb; ++kt) {
    const int k0 = kt * 64;
    __syncthreads();
    {
      int cb = t >> 6, row = t & 63;
      glds16(Kb + (size_t)(k0 + row) * 64 + cb * 8, &kbuf[t * 8]);
      glds16(Vb + (size_t)row * 2048 + k0 + cb * 8, &vbuf[t * 8]);
    }
    __syncthreads();
    if (kt > myqt) continue;
    f32x4 s[4] = {};
#pragma unroll
    for (int fc = 0; fc < 4; ++fc)
#pragma unroll
      for (int dk = 0; dk < 2; ++dk) {
        bf16x8 kf = *(const bf16x8*)&kbuf[((dk * 4 + lg) * 64 + fc * 16 + lrow) * 8];
        s[fc] = __builtin_amdgcn_mfma_f32_16x16x32_bf16(qf[dk], kf, s[fc], 0, 0, 0);
      }
#pragma unroll
    for (int r = 0; r < 4; ++r) {
      const int qg = wq0 + 4 * lg + r;
      const int q_ = 4 * lg + r;
      float* arow = attn_b + (size_t)qg * 2048 + k0;
#pragma unroll
      for (int fc = 0; fc < 4; ++fc) {
        const int kg = k0 + fc * 16 + lrow;
        const float pv = (kg <= qg) ? __expf(s[fc][r] + loglinv[r]) : 0.f;
        arow[fc * 16 + lrow] = pv;
        // scatter into per-wave P buffer in MFMA-A layout (XOR swizzled)
        const int k_ = fc * 16 + lrow;
        const int dl = q_ + 16 * ((k_ >> 3) & 3);
        const int kk = k_ >> 5, j = k_ & 7;
        int byteo = (kk * 64 + dl) * 16 + j * 2;
        byteo ^= ((kk * 8 + (dl >> 3)) & 7) << 4;
        *(unsigned short*)((char*)pbuf[wave] + byteo) = f2bf(pv);
      }
    }
#pragma unroll
    for (int kk = 0; kk < 2; ++kk) {
      int rbyte = (kk * 64 + lane) * 16;
      rbyte ^= ((kk * 8 + (lane >> 3)) & 7) << 4;
      bf16x8 pa = *(const bf16x8*)((char*)pbuf[wave] + rbyte);
#pragma unroll
      for (int fd = 0; fd < 4; ++fd) {
        bf16x8 vf = *(const bf16x8*)&vbuf[((kk * 4 + lg) * 64 + fd * 16 + lrow) * 8];
        oa[fd] = __builtin_amdgcn_mfma_f32_16x16x32_bf16(pa, vf, oa[fd], 0, 0, 0);
      }
    }
  }

  // -------- zero-fill non-causal region (vectorized), own tile rows
  {
    const int zc0 = (myqt + 1) * 16;
    for (int rr = 0; rr < 16; ++rr) {
      float4* arow = (float4*)(attn_b + (size_t)(wq0 + rr) * 2048);
      for (int c = zc0 + lane; c < 512; c += 64)
        arow[c] = make_float4(0.f, 0.f, 0.f, 0.f);
    }
  }

  // -------- ctx store [B,S,1024] bf16, own tile
  const int bidx = bh >> 4, h = bh & 15;
#pragma unroll
  for (int fd = 0; fd < 4; ++fd)
#pragma unroll
    for (int r = 0; r < 4; ++r) {
      const int qg = wq0 + 4 * lg + r;
      ctx[(size_t)(bidx * 2048 + qg) * 1024 + h * 64 + fd * 16 + lrow] =
          f2bf(oa[fd][r]);
    }
}

// ---------------------------------------------------------------- launch
extern "C" void kernel_launch(void* const* d_in, const int* in_sizes, int n_in,
                              void* d_out, int out_size, void* d_ws, size_t ws_size,
                              hipStream_t stream) {
  const float* q_in = (const float*)d_in[0];
  const float* k_in = (const float*)d_in[1];
  const float* v_in = (const float*)d_in[2];
  const float* Wq = (const float*)d_in[3];
  const float* bq = (const float*)d_in[4];
  const float* Wk = (const float*)d_in[5];
  const float* bk = (const float*)d_in[6];
  const float* Wv = (const float*)d_in[7];
  const float* bv = (const float*)d_in[8];
  const float* Wo = (const float*)d_in[9];
  const float* bo = (const float*)d_in[10];

  unsigned short* ws = (unsigned short*)d_ws;
  float* outp = (float*)d_out;

  // ws offsets in ushort units
  const size_t OXQ = 0, OXK = 4194304, OXV = 8388608;
  const size_t OWQ = 12582912, OWK = 13631488, OWV = 14680064, OWO = 15728640;
  const size_t OQ = 16777216, OK = 20971520, OV = 25165824;
  const size_t OTAB = 29360128;  // 2048*32 float2 = 262144 ushorts
  const size_t OVT = OXK;   // xk dead after QKV GEMM
  const size_t OCTX = OXQ;  // xq dead after QKV GEMM
  float2* rtab = (float2*)(ws + OTAB);

  cvt_all<<<dim3(512, 1, 8), 256, 0, stream>>>(q_in, k_in, v_in, Wq, Wk, Wv, Wo,
                                               ws, rtab);
  gemm_qkv<<<dim3(8, 32, 3), 256, 0, stream>>>(ws + OXQ, ws + OXK, ws + OXV,
                                               ws + OWQ, ws + OWK, ws + OWV,
                                               bq, bk, bv, rtab,
                                               ws + OQ, ws + OK, ws + OV);
  transpose_v<<<dim3(32, 32), 256, 0, stream>>>(ws + OV, ws + OVT);
  attn_kernel<<<dim3(16, 32), 512, 0, stream>>>(ws + OQ, ws + OK, ws + OVT,
                                                outp + 4194304, ws + OCTX);
  gemm_out<<<dim3(8, 32), 256, 0, stream>>>(ws + OCTX, ws + OWO, bo, outp);
}